// Round 1
// baseline (205.442 us; speedup 1.0000x reference)
//
#include <hip/hip_runtime.h>

// Problem: B=8, N=1024, C=768, H=12, D=64. Inputs fp32; internal bf16 MFMA.
// ws layout: wqkvT bf16[2304][768] | wprojT bf16[768][768] |
//   q,k bf16[B*H][N][D], vT bf16[B*H][D][N] | aout bf16[8192][768] (aliased as xb)

typedef unsigned short u16;
typedef short s16x8 __attribute__((ext_vector_type(8)));   // 8 bf16 = 4 VGPRs
typedef float f32x4 __attribute__((ext_vector_type(4)));
typedef u16   u16x8 __attribute__((ext_vector_type(8)));
typedef u16   u16x4 __attribute__((ext_vector_type(4)));

__device__ __forceinline__ u16 f2bf(float f) {
    unsigned int u = __builtin_bit_cast(unsigned int, f);
    u += 0x7FFFu + ((u >> 16) & 1u);      // RNE
    return (u16)(u >> 16);
}

// async global->LDS, 16B per lane. LDS dest must be WAVE-UNIFORM base;
// HW adds lane*16 (m97/m104-verified semantics).
__device__ __forceinline__ void gload16(const u16* g, u16* l) {
    __builtin_amdgcn_global_load_lds(
        (const __attribute__((address_space(1))) unsigned int*)g,
        (__attribute__((address_space(3))) unsigned int*)l, 16, 0, 0);
}

// ---------------------------------------------------------------------------
// Fused prep: x fp32->bf16 convert (blocks 0..3071) | w_qkv transpose
// (3072..4799) | w_proj transpose (4800..5375).
// ---------------------------------------------------------------------------
__global__ __launch_bounds__(256) void prep(
    const float* __restrict__ x, u16* __restrict__ xb,
    const float* __restrict__ wq, u16* __restrict__ wqT,
    const float* __restrict__ wp, u16* __restrict__ wpT) {
    __shared__ float ts[32][33];
    const int g = blockIdx.x, tid = threadIdx.x;
    if (g < 3072) {
        const size_t i = ((size_t)g * 256 + tid) * 8;
        float4 v0 = *(const float4*)(x + i);
        float4 v1 = *(const float4*)(x + i + 4);
        u16x8 p;
        p[0] = f2bf(v0.x); p[1] = f2bf(v0.y); p[2] = f2bf(v0.z); p[3] = f2bf(v0.w);
        p[4] = f2bf(v1.x); p[5] = f2bf(v1.y); p[6] = f2bf(v1.z); p[7] = f2bf(v1.w);
        *(u16x8*)(xb + i) = p;
        return;
    }
    const float* in; u16* out; int K, Nc, n0, k0;
    if (g < 4800) {
        int gg = g - 3072; in = wq; out = wqT; K = 768; Nc = 2304;
        n0 = (gg % 72) * 32; k0 = (gg / 72) * 32;
    } else {
        int gg = g - 4800; in = wp; out = wpT; K = 768; Nc = 768;
        n0 = (gg % 24) * 32; k0 = (gg / 24) * 32;
    }
    const int tx = tid & 31, ty = tid >> 5;
#pragma unroll
    for (int j = 0; j < 4; ++j) {
        int r = ty + j * 8;
        ts[r][tx] = in[(size_t)(k0 + r) * Nc + n0 + tx];
    }
    __syncthreads();
#pragma unroll
    for (int j = 0; j < 4; ++j) {
        int r = ty + j * 8;
        out[(size_t)(n0 + r) * K + k0 + tx] = f2bf(ts[tx][r]);
    }
}

// ---------------------------------------------------------------------------
// GEMM1: qkv = xb[8192][768] @ wqkvT^T, bf16. 8-phase counted-vmcnt template
// (T1+T2+T3+T4+T5), BM=BN=256, BK=64, 512 thr = 2x4 waves, per-wave 128x64.
// LDS 128KB: [2 dbuf][2 K-half] x (A 256x32 + B 256x32) bf16.
//
// Schedule invariants (hand-verified):
//  - Per K-tile: 4 phases {ks,nq} = (0,0),(0,1),(1,0),(1,1); A-frags read at
//    phases 0,2 and carried in regs; B-frags read every phase. 16 MFMA/phase.
//  - Staging per iter t: p0: Bks1(t+1)->other buf; p1: Aks0(t+2)->cur buf
//    (A-ks0 reads done at p0); p2: Bks0(t+2) (B-ks0 reads done p0,p1);
//    p3: Aks1(t+2) (A-ks1 reads done p2). Overwrite-safety via the phase-entry
//    barrier following the last reader phase.
//  - vmcnt(6) once per tile at p3: outstanding = 6 carried + 8 issued = 14;
//    drains oldest 8 = ALL of tile t+1. Steady carried = {Aks0,Bks0,Aks1}(t+2).
//    Never vmcnt(0) in the loop. Tail tiles wrap k0 (stage garbage, uniform
//    counts, in-bounds).
//  - Swizzle (involution, per 16-row group): col-group cg ^= (rowlocal>>1)&3.
//    Staged via pre-swizzled GLOBAL source (LDS dest stays linear, m104/m173);
//    read via qsw = quad ^ ((m15>>1)&3). 8-way b128 conflict -> 2-way (free).
// ---------------------------------------------------------------------------
template<bool SWAP, int NI>
__device__ __forceinline__ void mfma_pair(f32x4 (&acc)[8][4], const s16x8 (&av)[8],
                                          s16x8 bva, s16x8 bvb) {
#pragma unroll
    for (int mi = 0; mi < 8; ++mi) {
        if (SWAP) {   // D = C^T: row=d(quad*4+rg), col=token(m15)
            acc[mi][NI]     = __builtin_amdgcn_mfma_f32_16x16x32_bf16(bva, av[mi], acc[mi][NI], 0, 0, 0);
            acc[mi][NI + 1] = __builtin_amdgcn_mfma_f32_16x16x32_bf16(bvb, av[mi], acc[mi][NI + 1], 0, 0, 0);
        } else {      // D = C: row=token(quad*4+rg), col=d(m15)
            acc[mi][NI]     = __builtin_amdgcn_mfma_f32_16x16x32_bf16(av[mi], bva, acc[mi][NI], 0, 0, 0);
            acc[mi][NI + 1] = __builtin_amdgcn_mfma_f32_16x16x32_bf16(av[mi], bvb, acc[mi][NI + 1], 0, 0, 0);
        }
    }
}

#define PH_BAR()  asm volatile("s_barrier" ::: "memory")
#define PH_LGKM() asm volatile("s_waitcnt lgkmcnt(0)" ::: "memory")

template<bool SWAP>
__device__ __forceinline__ void qkv_loop(f32x4 (&acc)[8][4],
    const u16* __restrict__ Aq, const u16* __restrict__ Bt,
    u16* As, u16* Bs, int m0, int n0, int lane, int w) {
    const int m15 = lane & 15, quad = lane >> 4;
    const int wy = w >> 2, wx = w & 3;
    const int qsw8 = (quad ^ ((m15 >> 1) & 3)) * 8;            // read-side swizzle
    const int srow = lane >> 2;                                 // 0..15
    const int scg = ((lane & 3) ^ ((lane >> 3) & 3)) * 8;      // staged-source swizzle
    const int rg0 = w * 16, rg1 = (w + 8) * 16;                // this wave's 2 row groups
    const size_t ga0 = (size_t)(m0 + rg0 + srow) * 768 + scg;
    const size_t ga1 = (size_t)(m0 + rg1 + srow) * 768 + scg;
    const size_t gb0 = (size_t)(n0 + rg0 + srow) * 768 + scg;
    const size_t gb1 = (size_t)(n0 + rg1 + srow) * 768 + scg;

    auto stA = [&](int buf, int ks, int t) {
        const int k0 = t * 64 + ks * 32;
        u16* dst = As + ((buf * 2 + ks) << 13);
        gload16(Aq + ga0 + k0, dst + (rg0 << 5));
        gload16(Aq + ga1 + k0, dst + (rg1 << 5));
    };
    auto stB = [&](int buf, int ks, int t) {
        const int k0 = t * 64 + ks * 32;
        u16* dst = Bs + ((buf * 2 + ks) << 13);
        gload16(Bt + gb0 + k0, dst + (rg0 << 5));
        gload16(Bt + gb1 + k0, dst + (rg1 << 5));
    };

    // prologue: tile0 complete, tile1 {Aks0,Aks1,Bks0}; keep 6 ops in flight
    stA(0, 0, 0); stA(0, 1, 0); stB(0, 0, 0); stB(0, 1, 0);
    stA(1, 0, 1); stA(1, 1, 1); stB(1, 0, 1);
    asm volatile("s_waitcnt vmcnt(6)" ::: "memory");
    PH_BAR();

    const int arow = (wy * 128 + m15) * 32 + qsw8;   // + mi*512
    const int brow = (wx * 64 + m15) * 32 + qsw8;    // + ni*512

#pragma unroll 2
    for (int t = 0; t < 12; ++t) {
        const int cur = t & 1, nxt = cur ^ 1;
        const int t1 = (t + 1 < 12) ? t + 1 : 0;        // wrap: garbage stage, uniform counts
        const int t2 = (t + 2 < 12) ? t + 2 : t - 10;
        const u16* A0p = As + ((cur * 2 + 0) << 13);
        const u16* A1p = As + ((cur * 2 + 1) << 13);
        const u16* B0p = Bs + ((cur * 2 + 0) << 13);
        const u16* B1p = Bs + ((cur * 2 + 1) << 13);
        s16x8 av[8], bva, bvb;

        // ---- phase 0: ks0, ni {0,1}
#pragma unroll
        for (int mi = 0; mi < 8; ++mi)
            av[mi] = *(const s16x8*)(A0p + arow + mi * 512);
        bva = *(const s16x8*)(B0p + brow);
        bvb = *(const s16x8*)(B0p + brow + 512);
        stB(nxt, 1, t1);
        PH_BAR(); PH_LGKM();
        __builtin_amdgcn_s_setprio(1);
        mfma_pair<SWAP, 0>(acc, av, bva, bvb);
        __builtin_amdgcn_s_setprio(0);
        PH_BAR();

        // ---- phase 1: ks0, ni {2,3} (av carried)
        bva = *(const s16x8*)(B0p + brow + 1024);
        bvb = *(const s16x8*)(B0p + brow + 1536);
        stA(cur, 0, t2);                 // A-ks0 reads finished at p0
        PH_BAR(); PH_LGKM();
        __builtin_amdgcn_s_setprio(1);
        mfma_pair<SWAP, 2>(acc, av, bva, bvb);
        __builtin_amdgcn_s_setprio(0);
        PH_BAR();

        // ---- phase 2: ks1, ni {0,1}
#pragma unroll
        for (int mi = 0; mi < 8; ++mi)
            av[mi] = *(const s16x8*)(A1p + arow + mi * 512);
        bva = *(const s16x8*)(B1p + brow);
        bvb = *(const s16x8*)(B1p + brow + 512);
        stB(cur, 0, t2);                 // B-ks0 reads finished at p1
        PH_BAR(); PH_LGKM();
        __builtin_amdgcn_s_setprio(1);
        mfma_pair<SWAP, 0>(acc, av, bva, bvb);
        __builtin_amdgcn_s_setprio(0);
        PH_BAR();

        // ---- phase 3: ks1, ni {2,3} (av carried)
        bva = *(const s16x8*)(B1p + brow + 1024);
        bvb = *(const s16x8*)(B1p + brow + 1536);
        stA(cur, 1, t2);                 // A-ks1 reads finished at p2
        asm volatile("s_waitcnt vmcnt(6)" ::: "memory");  // tile t+1 fully landed
        PH_BAR(); PH_LGKM();
        __builtin_amdgcn_s_setprio(1);
        mfma_pair<SWAP, 2>(acc, av, bva, bvb);
        __builtin_amdgcn_s_setprio(0);
        PH_BAR();
    }
    asm volatile("s_waitcnt vmcnt(0)" ::: "memory");  // drain tail garbage loads
}

__global__ __launch_bounds__(512, 2) void gemm_qkv(
    const u16* __restrict__ Aq, const u16* __restrict__ Bt,
    u16* __restrict__ qb, u16* __restrict__ kb, u16* __restrict__ vbT) {
    __shared__ __align__(16) u16 As[2 * 2 * 8192];   // 64KB
    __shared__ __align__(16) u16 Bs[2 * 2 * 8192];   // 64KB
    const int tid = threadIdx.x;
    const int lane = tid & 63, w = tid >> 6;
    const int m15 = lane & 15, quad = lane >> 4;
    const int wy = w >> 2, wx = w & 3;
    // bijective XCD chunking: 288 = 8 * 36 exactly
    const int wg = (blockIdx.x & 7) * 36 + (blockIdx.x >> 3);
    const int mt = wg / 9, nt = wg - mt * 9;
    const int m0 = mt * 256, n0 = nt * 256;
    const int which = nt / 3;            // 0=q, 1=k, 2=v (block-uniform)

    f32x4 acc[8][4] = {};
    if (which < 2)
        qkv_loop<true>(acc, Aq, Bt, As, Bs, m0, n0, lane, w);   // C^T: pack along d
    else
        qkv_loop<false>(acc, Aq, Bt, As, Bs, m0, n0, lane, w);  // C: pack along token

    const int b  = (m0 + wy * 128) >> 10;
    const int r0 = (m0 + wy * 128) & 1023;
    const int n0p = n0 - which * 768;
    const int h = (n0p + wx * 64) >> 6;                 // wave-uniform head
    const size_t bhi = (size_t)(b * 12 + h);
    if (which == 2) {
        // normal orientation: quartet = 4 consecutive tokens, vbT token-minor
#pragma unroll
        for (int mi = 0; mi < 8; ++mi)
#pragma unroll
            for (int ni = 0; ni < 4; ++ni) {
                u16x4 pk;
#pragma unroll
                for (int rg = 0; rg < 4; ++rg) pk[rg] = f2bf(acc[mi][ni][rg]);
                const int d = ni * 16 + m15;
                const int tok = r0 + mi * 16 + (quad << 2);
                *(u16x4*)&vbT[(bhi * 64 + d) * 1024 + tok] = pk;
            }
    } else {
        // swapped orientation: quartet = 4 consecutive d, qb/kb d-minor
        u16* dst = which ? kb : qb;
#pragma unroll
        for (int mi = 0; mi < 8; ++mi)
#pragma unroll
            for (int ni = 0; ni < 4; ++ni) {
                u16x4 pk;
#pragma unroll
                for (int rg = 0; rg < 4; ++rg) pk[rg] = f2bf(acc[mi][ni][rg]);
                const int tok = r0 + mi * 16 + m15;
                const int d = ni * 16 + (quad << 2);
                *(u16x4*)&dst[(bhi * 1024 + tok) * 64 + d] = pk;
            }
    }
}

// ---------------------------------------------------------------------------
// GEMM2: out = aout[8192][768](bf16) @ wprojT^T + bias (fp32). BK=64, swizzle.
// ---------------------------------------------------------------------------
__global__ __launch_bounds__(256) void gemm_proj(
    const u16* __restrict__ A, const u16* __restrict__ Bt,
    const float* __restrict__ bias, float* __restrict__ out) {
    __shared__ __align__(16) u16 As[2][128 * 32];
    __shared__ __align__(16) u16 Bs[2][128 * 32];
    const int tid = threadIdx.x;
    const int lane = tid & 63, w = tid >> 6;
    const int m15 = lane & 15, quad = lane >> 4;
    const int wy = w >> 1, wx = w & 1;
    const int g = blockIdx.x;
    const int xcd = g & 7, s = g >> 3;
    const int yt = xcd * 8 + (s & 7), xt = s >> 3;
    const int m0 = yt * 128, n0 = xt * 128;
    const int srow16 = lane >> 2;
    const int scol = (lane & 3) * 8;

    f32x4 acc[4][4] = {};

    for (int k0 = 0; k0 < 768; k0 += 64) {
        __syncthreads();
#pragma unroll
        for (int j = 0; j < 2; ++j) {
            int rA = w * 32 + j * 16 + srow16;
            const u16* a0 = A  + (size_t)(m0 + rA) * 768 + k0 + scol;
            const u16* b0 = Bt + (size_t)(n0 + rA) * 768 + k0 + scol;
            gload16(a0,      &As[0][(w * 32 + j * 16) * 32]);
            gload16(a0 + 32, &As[1][(w * 32 + j * 16) * 32]);
            gload16(b0,      &Bs[0][(w * 32 + j * 16) * 32]);
            gload16(b0 + 32, &Bs[1][(w * 32 + j * 16) * 32]);
        }
        __syncthreads();
#pragma unroll
        for (int h = 0; h < 2; ++h) {
            s16x8 av[4], bv[4];
#pragma unroll
            for (int ri = 0; ri < 4; ++ri)
                av[ri] = *(const s16x8*)&As[h][(wy * 64 + ri * 16 + m15) * 32 + quad * 8];
#pragma unroll
            for (int ci = 0; ci < 4; ++ci)
                bv[ci] = *(const s16x8*)&Bs[h][(wx * 64 + ci * 16 + m15) * 32 + quad * 8];
#pragma unroll
            for (int ri = 0; ri < 4; ++ri)
#pragma unroll
                for (int ci = 0; ci < 4; ++ci)
                    acc[ri][ci] = __builtin_amdgcn_mfma_f32_16x16x32_bf16(av[ri], bv[ci], acc[ri][ci], 0, 0, 0);
        }
    }

#pragma unroll
    for (int ri = 0; ri < 4; ++ri) {
        int mb = m0 + wy * 64 + ri * 16 + (quad << 2);
#pragma unroll
        for (int ci = 0; ci < 4; ++ci) {
            int n = n0 + wx * 64 + ci * 16 + m15;
            float bv_ = bias[n];
#pragma unroll
            for (int rg = 0; rg < 4; ++rg)
                out[(size_t)(mb + rg) * 768 + n] = acc[ri][ci][rg] + bv_;
        }
    }
}

// ---------------------------------------------------------------------------
// MFMA flash attention v3: S^T formulation.
//   S^T = K·Q^T (A=K-frag, B=Q-frag): C-reg quartet = 4 consecutive KEYS of
//   one query -> P written as packed b64 (4 ops, conflict-free) instead of 16
//   conflicted b16 stores; P read back as b128 A-frags (exact A layout).
//   2 query-sets per wave (32 q/wave, 128 q/block): K/V frag reads shared.
//   Fixed-max softmax (R4-verified), l via ones-column MFMA (unchanged).
// grid(768): xcd swizzle, 3 blocks/CU. LDS 36.9 KB.
// ---------------------------------------------------------------------------
#define KS 72   // LDS stride (64+8): b128/b64 accesses conflict-free

__global__ __launch_bounds__(256) void attn_mfma(
    const u16* __restrict__ qb, const u16* __restrict__ kb,
    const u16* __restrict__ vbT, u16* __restrict__ aout) {
    __shared__ __align__(16) u16 Ks[64 * KS];
    __shared__ __align__(16) u16 Vs[64 * KS];
    __shared__ __align__(16) u16 Ps[8][16 * KS];   // [wave*2+qs]
    const int tid = threadIdx.x, lane = tid & 63, w = tid >> 6;
    const int m15 = lane & 15, quad = lane >> 4;
    const int g = blockIdx.x;                      // 768 blocks
    const int xcd = g & 7, s = g >> 3;             // s 0..95
    const int bh = xcd * 12 + (s % 12);
    const int q0 = (s / 12) * 128;

    // Q B-frags (2 sets of 16 queries), in registers for the whole kernel
    s16x8 aq[2][2];
#pragma unroll
    for (int qs = 0; qs < 2; ++qs) {
        const u16* qp = qb + ((size_t)bh * 1024 + q0 + w * 32 + qs * 16 + m15) * 64 + quad * 8;
        aq[qs][0] = *(const s16x8*)qp;
        aq[qs][1] = *(const s16x8*)(qp + 32);
    }

    s16x8 bones;
#pragma unroll
    for (int j = 0; j < 8; ++j) bones[j] = (m15 == 0) ? (short)0x3F80 : (short)0;

    f32x4 oacc[2][4] = {};
    f32x4 lacc[2] = {};

    const int srow = tid >> 2;           // 0..63
    const int soff = (tid & 3) * 16;
    const u16* kbase = kb + (size_t)bh * 1024 * 64;
    const u16* vbase = vbT + (size_t)bh * 64 * 1024;
    const float CE   = 0.125f * 1.44269504f;   // SCALE * log2(e)
    const float MOFF = 12.0f * 1.44269504f;    // fixed max * log2(e)

    for (int kt = 0; kt < 16; ++kt) {
        __syncthreads();
        const u16* kpp = kbase + ((size_t)kt * 64 + srow) * 64 + soff;
        const u16* vpp = vbase + (size_t)srow * 1024 + kt * 64 + soff;
        *(u16x8*)&Ks[srow * KS + soff]     = *(const u16x8*)kpp;
        *(u16x8*)&Ks[srow * KS + soff + 8] = *(const u16x8*)(kpp + 8);
        *(u16x8*)&Vs[srow * KS + soff]     = *(const u16x8*)vpp;
        *(u16x8*)&Vs[srow * KS + soff + 8] = *(const u16x8*)(vpp + 8);
        __syncthreads();

        // --- S^T[key][q]: A = K rows, B = Q (both q-sets share K frags) ---
        f32x4 sacc[2][4] = {};
#pragma unroll
        for (int t = 0; t < 4; ++t)
#pragma unroll
            for (int ch = 0; ch < 2; ++ch) {
                s16x8 ak = *(const s16x8*)&Ks[(t * 16 + m15) * KS + quad * 8 + 32 * ch];
                sacc[0][t] = __builtin_amdgcn_mfma_f32_16x16x32_bf16(ak, aq[0][ch], sacc[0][t], 0, 0, 0);
                sacc[1][t] = __builtin_amdgcn_mfma_f32_16x16x32_bf16(ak, aq[1][ch], sacc[1][t], 0, 0, 0);
            }

        // --- P = exp2(s*CE - MOFF): 4 consecutive keys/reg -> packed b64 ---
#pragma unroll
        for (int qs = 0; qs < 2; ++qs)
#pragma unroll
            for (int t = 0; t < 4; ++t) {
                u16x4 pk;
#pragma unroll
                for (int reg = 0; reg < 4; ++reg) {
                    float pv = __builtin_amdgcn_exp2f(sacc[qs][t][reg] * CE - MOFF);
                    unsigned int u = __builtin_bit_cast(unsigned int, pv);
                    pk[reg] = (u16)(u >> 16);
                }
                *(u16x4*)&Ps[w * 2 + qs][m15 * KS + t * 16 + quad * 4] = pk;
            }
        // no barrier: Ps[w*2+qs] is wave-private

        // --- P A-frags, l (ones-column), PV (V frags shared across q-sets) ---
        s16x8 ap[2][2];
#pragma unroll
        for (int qs = 0; qs < 2; ++qs) {
            ap[qs][0] = *(const s16x8*)&Ps[w * 2 + qs][m15 * KS + quad * 8];
            ap[qs][1] = *(const s16x8*)&Ps[w * 2 + qs][m15 * KS + quad * 8 + 32];
#pragma unroll
            for (int ch = 0; ch < 2; ++ch)
                lacc[qs] = __builtin_amdgcn_mfma_f32_16x16x32_bf16(ap[qs][ch], bones, lacc[qs], 0, 0, 0);
        }
#pragma unroll
        for (int di = 0; di < 4; ++di)
#pragma unroll
            for (int ch = 0; ch < 2; ++ch) {
                s16x8 bv = *(const s16x8*)&Vs[(di * 16 + m15) * KS + quad * 8 + 32 * ch];
                oacc[0][di] = __builtin_amdgcn_mfma_f32_16x16x32_bf16(ap[0][ch], bv, oacc[0][di], 0, 0, 0);
                oacc[1][di] = __builtin_amdgcn_mfma_f32_16x16x32_bf16(ap[1][ch], bv, oacc[1][di], 0, 0, 0);
            }
    }

    const int b = bh / 12, h = bh - b * 12;
#pragma unroll
    for (int qs = 0; qs < 2; ++qs) {
        float linv[4];
#pragma unroll
        for (int reg = 0; reg < 4; ++reg)
            linv[reg] = 1.0f / __shfl(lacc[qs][reg], lane & 48);
#pragma unroll
        for (int di = 0; di < 4; ++di)
#pragma unroll
            for (int reg = 0; reg < 4; ++reg) {
                int q = q0 + w * 32 + qs * 16 + quad * 4 + reg;
                aout[((size_t)b * 1024 + q) * 768 + h * 64 + di * 16 + m15] =
                    f2bf(oacc[qs][di][reg] * linv[reg]);
            }
    }
}

// ---------------------------------------------------------------------------
extern "C" void kernel_launch(void* const* d_in, const int* in_sizes, int n_in,
                              void* d_out, int out_size, void* d_ws, size_t ws_size,
                              hipStream_t stream) {
    const float* x      = (const float*)d_in[0];
    const float* w_qkv  = (const float*)d_in[1];
    const float* w_proj = (const float*)d_in[2];
    const float* b_proj = (const float*)d_in[3];
    float* out = (float*)d_out;

    char* ws = (char*)d_ws;
    u16* wqkvT  = (u16*)ws;  ws += (size_t)2304 * 768 * 2;
    u16* wprojT = (u16*)ws;  ws += (size_t)768 * 768 * 2;
    u16* qb     = (u16*)ws;  ws += (size_t)96 * 1024 * 64 * 2;
    u16* kb     = (u16*)ws;  ws += (size_t)96 * 1024 * 64 * 2;
    u16* vbT    = (u16*)ws;  ws += (size_t)96 * 1024 * 64 * 2;
    u16* aout   = (u16*)ws;  ws += (size_t)8192 * 768 * 2;
    u16* xb     = aout;   // lifetimes don't overlap

    prep<<<dim3(5376), 256, 0, stream>>>(x, xb, w_qkv, wqkvT, w_proj, wprojT);
    gemm_qkv<<<dim3(288), 512, 0, stream>>>(xb, wqkvT, qb, kb, vbT);
    attn_mfma<<<dim3(768), 256, 0, stream>>>(qb, kb, vbT, aout);
    gemm_proj<<<dim3(384), 256, 0, stream>>>(aout, wprojT, b_proj, out);
}

// Round 2
// 190.118 us; speedup vs baseline: 1.0806x; 1.0806x over previous
//
#include <hip/hip_runtime.h>

// Problem: B=8, N=1024, C=768, H=12, D=64. Inputs fp32; internal bf16 MFMA.
// ws layout: wqkvT bf16[2304][768] | wprojT bf16[768][768] |
//   q,k bf16[B*H][N][D], vT bf16[B*H][D][N] | aout bf16[8192][768] (aliased as xb)

typedef unsigned short u16;
typedef short s16x8 __attribute__((ext_vector_type(8)));   // 8 bf16 = 4 VGPRs
typedef float f32x4 __attribute__((ext_vector_type(4)));
typedef u16   u16x8 __attribute__((ext_vector_type(8)));
typedef u16   u16x4 __attribute__((ext_vector_type(4)));

__device__ __forceinline__ u16 f2bf(float f) {
    unsigned int u = __builtin_bit_cast(unsigned int, f);
    u += 0x7FFFu + ((u >> 16) & 1u);      // RNE
    return (u16)(u >> 16);
}

// async global->LDS, 16B per lane. LDS dest must be WAVE-UNIFORM base;
// HW adds lane*16 (m97/m104-verified semantics).
__device__ __forceinline__ void gload16(const u16* g, u16* l) {
    __builtin_amdgcn_global_load_lds(
        (const __attribute__((address_space(1))) unsigned int*)g,
        (__attribute__((address_space(3))) unsigned int*)l, 16, 0, 0);
}

// ---------------------------------------------------------------------------
// Fused prep: x fp32->bf16 convert (blocks 0..3071) | w_qkv transpose
// (3072..4799) | w_proj transpose (4800..5375).
// ---------------------------------------------------------------------------
__global__ __launch_bounds__(256) void prep(
    const float* __restrict__ x, u16* __restrict__ xb,
    const float* __restrict__ wq, u16* __restrict__ wqT,
    const float* __restrict__ wp, u16* __restrict__ wpT) {
    __shared__ float ts[32][33];
    const int g = blockIdx.x, tid = threadIdx.x;
    if (g < 3072) {
        const size_t i = ((size_t)g * 256 + tid) * 8;
        float4 v0 = *(const float4*)(x + i);
        float4 v1 = *(const float4*)(x + i + 4);
        u16x8 p;
        p[0] = f2bf(v0.x); p[1] = f2bf(v0.y); p[2] = f2bf(v0.z); p[3] = f2bf(v0.w);
        p[4] = f2bf(v1.x); p[5] = f2bf(v1.y); p[6] = f2bf(v1.z); p[7] = f2bf(v1.w);
        *(u16x8*)(xb + i) = p;
        return;
    }
    const float* in; u16* out; int K, Nc, n0, k0;
    if (g < 4800) {
        int gg = g - 3072; in = wq; out = wqT; K = 768; Nc = 2304;
        n0 = (gg % 72) * 32; k0 = (gg / 72) * 32;
    } else {
        int gg = g - 4800; in = wp; out = wpT; K = 768; Nc = 768;
        n0 = (gg % 24) * 32; k0 = (gg / 24) * 32;
    }
    const int tx = tid & 31, ty = tid >> 5;
#pragma unroll
    for (int j = 0; j < 4; ++j) {
        int r = ty + j * 8;
        ts[r][tx] = in[(size_t)(k0 + r) * Nc + n0 + tx];
    }
    __syncthreads();
#pragma unroll
    for (int j = 0; j < 4; ++j) {
        int r = ty + j * 8;
        out[(size_t)(n0 + r) * K + k0 + tx] = f2bf(ts[tx][r]);
    }
}

// ---------------------------------------------------------------------------
// Shared 128x128 GEMM K-loop: BK=32, counted-vmcnt double-buffer (T4),
// 4 waves (2x2, per-wave 64x64), 4 blocks/CU co-resident (the overlap engine,
// m114). Per K-step: stage next tile (4 gload16/wave) -> vmcnt(4) (never 0:
// current buf landed, next stays in flight) -> barrier -> 8 ds_read_b128 ->
// 16 MFMA (setprio-wrapped) -> barrier. Zero-conflict XOR swizzle on staged
// source + read addr (round-1 verified, SQ_LDS_BANK_CONFLICT=0).
// Race-freedom: stage(s+1) overwrites buf[cur^1], last read at step s-1,
// whose reads complete (compiler lgkm) before its MFMA, before BAR2, before
// this stage's issue. vmcnt(4) drains exactly the 4 oldest = buf[cur] loads.
// ---------------------------------------------------------------------------
template<bool SWAP>
__device__ __forceinline__ void gemm_loop_128(
    f32x4 (&acc)[4][4], const u16* __restrict__ A, const u16* __restrict__ B,
    u16* As, u16* Bs, int m0, int n0, int lane, int w) {
    const int m15 = lane & 15, quad = lane >> 4;
    const int wy = w >> 1, wx = w & 1;
    const int qsw8 = (quad ^ ((m15 >> 1) & 3)) * 8;        // read-side swizzle
    const int srow16 = lane >> 2;                           // 0..15
    const int scg = ((lane & 3) ^ ((lane >> 3) & 3)) * 8;  // staged-source swizzle
    const size_t gA = (size_t)(m0 + w * 32 + srow16) * 768 + scg;
    const size_t gB = (size_t)(n0 + w * 32 + srow16) * 768 + scg;

    auto stage = [&](int buf, int s) {
        const int k0 = (s < 24 ? s : 0) * 32;   // wrap: harmless garbage, uniform count
        u16* da = As + buf * 4096 + (w * 32) * 32;
        u16* db = Bs + buf * 4096 + (w * 32) * 32;
        gload16(A + gA + k0,            da);
        gload16(A + gA + 16 * 768 + k0, da + 16 * 32);
        gload16(B + gB + k0,            db);
        gload16(B + gB + 16 * 768 + k0, db + 16 * 32);
    };

    stage(0, 0);
    const int arow = (wy * 64 + m15) * 32 + qsw8;   // + ri*512
    const int brow = (wx * 64 + m15) * 32 + qsw8;   // + ci*512

#pragma unroll 2
    for (int s = 0; s < 24; ++s) {
        const int cur = s & 1;
        stage(cur ^ 1, s + 1);
        asm volatile("s_waitcnt vmcnt(4)" ::: "memory");
        __builtin_amdgcn_s_barrier();
        const u16* Ap = As + cur * 4096;
        const u16* Bp = Bs + cur * 4096;
        s16x8 av[4], bv[4];
#pragma unroll
        for (int ri = 0; ri < 4; ++ri)
            av[ri] = *(const s16x8*)(Ap + arow + ri * 512);
#pragma unroll
        for (int ci = 0; ci < 4; ++ci)
            bv[ci] = *(const s16x8*)(Bp + brow + ci * 512);
        __builtin_amdgcn_s_setprio(1);
#pragma unroll
        for (int ri = 0; ri < 4; ++ri)
#pragma unroll
            for (int ci = 0; ci < 4; ++ci) {
                if (SWAP)
                    acc[ri][ci] = __builtin_amdgcn_mfma_f32_16x16x32_bf16(bv[ci], av[ri], acc[ri][ci], 0, 0, 0);
                else
                    acc[ri][ci] = __builtin_amdgcn_mfma_f32_16x16x32_bf16(av[ri], bv[ci], acc[ri][ci], 0, 0, 0);
            }
        __builtin_amdgcn_s_setprio(0);
        __builtin_amdgcn_s_barrier();
    }
}

// ---------------------------------------------------------------------------
// GEMM1: qkv = xb[8192][768] @ wqkvT^T, bf16. 128x128 tiles, 1152 blocks
// (64x18), XCD swizzle, 4 blocks/CU. q/k use SWAP (C^T: acc quartet runs
// along d) -> packed u16x4 stores; v normal -> packed u16x4 along tokens.
// ---------------------------------------------------------------------------
__global__ __launch_bounds__(256, 4) void gemm_qkv(
    const u16* __restrict__ Aq, const u16* __restrict__ Bt,
    u16* __restrict__ qb, u16* __restrict__ kb, u16* __restrict__ vbT) {
    __shared__ __align__(16) u16 As[2 * 128 * 32];   // 16KB
    __shared__ __align__(16) u16 Bs[2 * 128 * 32];   // 16KB
    const int tid = threadIdx.x;
    const int lane = tid & 63, w = tid >> 6;
    const int m15 = lane & 15, quad = lane >> 4;
    const int wy = w >> 1, wx = w & 1;
    const int g = blockIdx.x;
    const int xcd = g & 7, s = g >> 3;               // s 0..143
    const int yt = xcd * 8 + (s & 7), xt = s >> 3;   // yt 0..63, xt 0..17
    const int m0 = yt * 128, n0 = xt * 128;
    const int which = xt / 6;                        // 0=q, 1=k, 2=v (block-uniform)

    f32x4 acc[4][4] = {};
    if (which < 2)
        gemm_loop_128<true >(acc, Aq, Bt, As, Bs, m0, n0, lane, w);
    else
        gemm_loop_128<false>(acc, Aq, Bt, As, Bs, m0, n0, lane, w);

    const int b   = m0 >> 10;
    const int r0  = (m0 & 1023) + wy * 64;
    const int n0p = n0 - which * 768;
    const int h   = (n0p >> 6) + wx;                 // wave-uniform head
    const size_t bhi = (size_t)(b * 12 + h);
    if (which == 2) {
        // normal orientation: quartet = 4 consecutive tokens, vbT token-minor
#pragma unroll
        for (int ri = 0; ri < 4; ++ri)
#pragma unroll
            for (int ci = 0; ci < 4; ++ci) {
                u16x4 pk;
#pragma unroll
                for (int rg = 0; rg < 4; ++rg) pk[rg] = f2bf(acc[ri][ci][rg]);
                const int d   = ci * 16 + m15;
                const int tok = r0 + ri * 16 + (quad << 2);
                *(u16x4*)&vbT[(bhi * 64 + d) * 1024 + tok] = pk;
            }
    } else {
        // swapped orientation: quartet = 4 consecutive d, qb/kb d-minor
        u16* dst = which ? kb : qb;
#pragma unroll
        for (int ri = 0; ri < 4; ++ri)
#pragma unroll
            for (int ci = 0; ci < 4; ++ci) {
                u16x4 pk;
#pragma unroll
                for (int rg = 0; rg < 4; ++rg) pk[rg] = f2bf(acc[ri][ci][rg]);
                const int tok = r0 + ri * 16 + m15;
                const int d   = ci * 16 + (quad << 2);
                *(u16x4*)&dst[(bhi * 1024 + tok) * 64 + d] = pk;
            }
    }
}

// ---------------------------------------------------------------------------
// GEMM2: out = aout[8192][768](bf16) @ wprojT^T + bias (fp32). Same loop.
// 384 blocks (64x6), XCD swizzle, 4 blocks/CU.
// ---------------------------------------------------------------------------
__global__ __launch_bounds__(256, 4) void gemm_proj(
    const u16* __restrict__ A, const u16* __restrict__ Bt,
    const float* __restrict__ bias, float* __restrict__ out) {
    __shared__ __align__(16) u16 As[2 * 128 * 32];
    __shared__ __align__(16) u16 Bs[2 * 128 * 32];
    const int tid = threadIdx.x;
    const int lane = tid & 63, w = tid >> 6;
    const int m15 = lane & 15, quad = lane >> 4;
    const int wy = w >> 1, wx = w & 1;
    const int g = blockIdx.x;
    const int xcd = g & 7, s = g >> 3;               // s 0..47
    const int yt = xcd * 8 + (s & 7), xt = s >> 3;   // yt 0..63, xt 0..5
    const int m0 = yt * 128, n0 = xt * 128;

    f32x4 acc[4][4] = {};
    gemm_loop_128<false>(acc, A, Bt, As, Bs, m0, n0, lane, w);

#pragma unroll
    for (int ri = 0; ri < 4; ++ri) {
        int mb = m0 + wy * 64 + ri * 16 + (quad << 2);
#pragma unroll
        for (int ci = 0; ci < 4; ++ci) {
            int n = n0 + wx * 64 + ci * 16 + m15;
            float bv_ = bias[n];
#pragma unroll
            for (int rg = 0; rg < 4; ++rg)
                out[(size_t)(mb + rg) * 768 + n] = acc[ri][ci][rg] + bv_;
        }
    }
}

// ---------------------------------------------------------------------------
// MFMA flash attention v3: S^T formulation.
//   S^T = K·Q^T (A=K-frag, B=Q-frag): C-reg quartet = 4 consecutive KEYS of
//   one query -> P written as packed b64 (4 ops, conflict-free) instead of 16
//   conflicted b16 stores; P read back as b128 A-frags (exact A layout).
//   2 query-sets per wave (32 q/wave, 128 q/block): K/V frag reads shared.
//   Fixed-max softmax (R4-verified), l via ones-column MFMA (unchanged).
// grid(768): xcd swizzle, 3 blocks/CU. LDS 36.9 KB.
// ---------------------------------------------------------------------------
#define KS 72   // LDS stride (64+8): b128/b64 accesses conflict-free

__global__ __launch_bounds__(256) void attn_mfma(
    const u16* __restrict__ qb, const u16* __restrict__ kb,
    const u16* __restrict__ vbT, u16* __restrict__ aout) {
    __shared__ __align__(16) u16 Ks[64 * KS];
    __shared__ __align__(16) u16 Vs[64 * KS];
    __shared__ __align__(16) u16 Ps[8][16 * KS];   // [wave*2+qs]
    const int tid = threadIdx.x, lane = tid & 63, w = tid >> 6;
    const int m15 = lane & 15, quad = lane >> 4;
    const int g = blockIdx.x;                      // 768 blocks
    const int xcd = g & 7, s = g >> 3;             // s 0..95
    const int bh = xcd * 12 + (s % 12);
    const int q0 = (s / 12) * 128;

    // Q B-frags (2 sets of 16 queries), in registers for the whole kernel
    s16x8 aq[2][2];
#pragma unroll
    for (int qs = 0; qs < 2; ++qs) {
        const u16* qp = qb + ((size_t)bh * 1024 + q0 + w * 32 + qs * 16 + m15) * 64 + quad * 8;
        aq[qs][0] = *(const s16x8*)qp;
        aq[qs][1] = *(const s16x8*)(qp + 32);
    }

    s16x8 bones;
#pragma unroll
    for (int j = 0; j < 8; ++j) bones[j] = (m15 == 0) ? (short)0x3F80 : (short)0;

    f32x4 oacc[2][4] = {};
    f32x4 lacc[2] = {};

    const int srow = tid >> 2;           // 0..63
    const int soff = (tid & 3) * 16;
    const u16* kbase = kb + (size_t)bh * 1024 * 64;
    const u16* vbase = vbT + (size_t)bh * 64 * 1024;
    const float CE   = 0.125f * 1.44269504f;   // SCALE * log2(e)
    const float MOFF = 12.0f * 1.44269504f;    // fixed max * log2(e)

    for (int kt = 0; kt < 16; ++kt) {
        __syncthreads();
        const u16* kpp = kbase + ((size_t)kt * 64 + srow) * 64 + soff;
        const u16* vpp = vbase + (size_t)srow * 1024 + kt * 64 + soff;
        *(u16x8*)&Ks[srow * KS + soff]     = *(const u16x8*)kpp;
        *(u16x8*)&Ks[srow * KS + soff + 8] = *(const u16x8*)(kpp + 8);
        *(u16x8*)&Vs[srow * KS + soff]     = *(const u16x8*)vpp;
        *(u16x8*)&Vs[srow * KS + soff + 8] = *(const u16x8*)(vpp + 8);
        __syncthreads();

        // --- S^T[key][q]: A = K rows, B = Q (both q-sets share K frags) ---
        f32x4 sacc[2][4] = {};
#pragma unroll
        for (int t = 0; t < 4; ++t)
#pragma unroll
            for (int ch = 0; ch < 2; ++ch) {
                s16x8 ak = *(const s16x8*)&Ks[(t * 16 + m15) * KS + quad * 8 + 32 * ch];
                sacc[0][t] = __builtin_amdgcn_mfma_f32_16x16x32_bf16(ak, aq[0][ch], sacc[0][t], 0, 0, 0);
                sacc[1][t] = __builtin_amdgcn_mfma_f32_16x16x32_bf16(ak, aq[1][ch], sacc[1][t], 0, 0, 0);
            }

        // --- P = exp2(s*CE - MOFF): 4 consecutive keys/reg -> packed b64 ---
#pragma unroll
        for (int qs = 0; qs < 2; ++qs)
#pragma unroll
            for (int t = 0; t < 4; ++t) {
                u16x4 pk;
#pragma unroll
                for (int reg = 0; reg < 4; ++reg) {
                    float pv = __builtin_amdgcn_exp2f(sacc[qs][t][reg] * CE - MOFF);
                    unsigned int u = __builtin_bit_cast(unsigned int, pv);
                    pk[reg] = (u16)(u >> 16);
                }
                *(u16x4*)&Ps[w * 2 + qs][m15 * KS + t * 16 + quad * 4] = pk;
            }
        // no barrier: Ps[w*2+qs] is wave-private

        // --- P A-frags, l (ones-column), PV (V frags shared across q-sets) ---
        s16x8 ap[2][2];
#pragma unroll
        for (int qs = 0; qs < 2; ++qs) {
            ap[qs][0] = *(const s16x8*)&Ps[w * 2 + qs][m15 * KS + quad * 8];
            ap[qs][1] = *(const s16x8*)&Ps[w * 2 + qs][m15 * KS + quad * 8 + 32];
#pragma unroll
            for (int ch = 0; ch < 2; ++ch)
                lacc[qs] = __builtin_amdgcn_mfma_f32_16x16x32_bf16(ap[qs][ch], bones, lacc[qs], 0, 0, 0);
        }
#pragma unroll
        for (int di = 0; di < 4; ++di)
#pragma unroll
            for (int ch = 0; ch < 2; ++ch) {
                s16x8 bv = *(const s16x8*)&Vs[(di * 16 + m15) * KS + quad * 8 + 32 * ch];
                oacc[0][di] = __builtin_amdgcn_mfma_f32_16x16x32_bf16(ap[0][ch], bv, oacc[0][di], 0, 0, 0);
                oacc[1][di] = __builtin_amdgcn_mfma_f32_16x16x32_bf16(ap[1][ch], bv, oacc[1][di], 0, 0, 0);
            }
    }

    const int b = bh / 12, h = bh - b * 12;
#pragma unroll
    for (int qs = 0; qs < 2; ++qs) {
        float linv[4];
#pragma unroll
        for (int reg = 0; reg < 4; ++reg)
            linv[reg] = 1.0f / __shfl(lacc[qs][reg], lane & 48);
#pragma unroll
        for (int di = 0; di < 4; ++di)
#pragma unroll
            for (int reg = 0; reg < 4; ++reg) {
                int q = q0 + w * 32 + qs * 16 + quad * 4 + reg;
                aout[((size_t)b * 1024 + q) * 768 + h * 64 + di * 16 + m15] =
                    f2bf(oacc[qs][di][reg] * linv[reg]);
            }
    }
}

// ---------------------------------------------------------------------------
extern "C" void kernel_launch(void* const* d_in, const int* in_sizes, int n_in,
                              void* d_out, int out_size, void* d_ws, size_t ws_size,
                              hipStream_t stream) {
    const float* x      = (const float*)d_in[0];
    const float* w_qkv  = (const float*)d_in[1];
    const float* w_proj = (const float*)d_in[2];
    const float* b_proj = (const float*)d_in[3];
    float* out = (float*)d_out;

    char* ws = (char*)d_ws;
    u16* wqkvT  = (u16*)ws;  ws += (size_t)2304 * 768 * 2;
    u16* wprojT = (u16*)ws;  ws += (size_t)768 * 768 * 2;
    u16* qb     = (u16*)ws;  ws += (size_t)96 * 1024 * 64 * 2;
    u16* kb     = (u16*)ws;  ws += (size_t)96 * 1024 * 64 * 2;
    u16* vbT    = (u16*)ws;  ws += (size_t)96 * 1024 * 64 * 2;
    u16* aout   = (u16*)ws;  ws += (size_t)8192 * 768 * 2;
    u16* xb     = aout;   // lifetimes don't overlap

    prep<<<dim3(5376), 256, 0, stream>>>(x, xb, w_qkv, wqkvT, w_proj, wprojT);
    gemm_qkv<<<dim3(1152), 256, 0, stream>>>(xb, wqkvT, qb, kb, vbT);
    attn_mfma<<<dim3(768), 256, 0, stream>>>(qb, kb, vbT, aout);
    gemm_proj<<<dim3(384), 256, 0, stream>>>(aout, wprojT, b_proj, out);
}